// Round 11
// baseline (1654.789 us; speedup 1.0000x reference)
//
#include <hip/hip_runtime.h>
#include <math.h>

#define N_ROWS 65536

typedef short short8 __attribute__((ext_vector_type(8)));
typedef float f32x4 __attribute__((ext_vector_type(4)));

__device__ __forceinline__ float gelu_f(float x) {
  float x3 = x * x * x;
  float t = tanhf(0.7978845608028654f * (x + 0.044715f * x3));
  return 0.5f * x * (1.0f + t);
}

__device__ __forceinline__ unsigned short f2bf(float f) {
  unsigned u = __float_as_uint(f);
  unsigned r = u + 0x7fffu + ((u >> 16) & 1u);
  return (unsigned short)(r >> 16);
}
__device__ __forceinline__ float bf2f(unsigned short h) {
  return __uint_as_float(((unsigned)h) << 16);
}

// RNE split (one-time weight prep)
__device__ __forceinline__ void split3(float v, unsigned short& p0,
                                       unsigned short& p1, unsigned short& p2) {
  p0 = f2bf(v);
  float r = v - bf2f(p0);
  p1 = f2bf(r);
  r -= bf2f(p1);
  p2 = f2bf(r);
}

// cheap split: round-half-up planes 0/1 (<=0.5 ulp, exact residuals), RNE last
__device__ __forceinline__ void split3f(float v, unsigned short& p0,
                                        unsigned short& p1, unsigned short& p2) {
  unsigned u = __float_as_uint(v);
  unsigned h0 = (u + 0x8000u) & 0xffff0000u;
  float r = v - __uint_as_float(h0);
  unsigned u1 = __float_as_uint(r);
  unsigned h1 = (u1 + 0x8000u) & 0xffff0000u;
  float r2 = r - __uint_as_float(h1);
  p0 = (unsigned short)(h0 >> 16);
  p1 = (unsigned short)(h1 >> 16);
  p2 = f2bf(r2);
}

// split a pair of floats, pack each plane into one dword (lo | hi<<16).
// all scalars -> guaranteed registers (no punned local arrays -> no scratch).
__device__ __forceinline__ void split2pack(float x, float y, unsigned& o0,
                                           unsigned& o1, unsigned& o2) {
  unsigned short x0, x1, x2, y0, y1, y2;
  split3f(x, x0, x1, x2);
  split3f(y, y0, y1, y2);
  o0 = (unsigned)x0 | ((unsigned)y0 << 16);
  o1 = (unsigned)x1 | ((unsigned)y1 << 16);
  o2 = (unsigned)x2 | ((unsigned)y2 << 16);
}

__device__ __forceinline__ f32x4 mfma16(short8 a, short8 b, f32x4 c) {
  return __builtin_amdgcn_mfma_f32_16x16x32_bf16(a, b, c, 0, 0, 0);
}

// ---------------- fp32 GEMM (enc0): C = gelu(A @ W + b) ----------------
template <bool GELU>
__global__ __launch_bounds__(256) void gemm_kernel(
    const float* __restrict__ A, const float* __restrict__ W,
    const float* __restrict__ bias, float* __restrict__ C,
    int din, int dout) {
  __shared__ float As[16][132];
  __shared__ float Ws[16][132];
  int t = threadIdx.x;
  int tx = t & 15, ty = t >> 4;
  int c0 = blockIdx.x * 128;
  int r0 = blockIdx.y * 128;

  float acc[8][8];
#pragma unroll
  for (int i = 0; i < 8; ++i)
#pragma unroll
    for (int j = 0; j < 8; ++j) acc[i][j] = 0.0f;

  int kchunks = din >> 4;
  for (int kc = 0; kc < kchunks; ++kc) {
    int k0 = kc << 4;
    __syncthreads();
#pragma unroll
    for (int it = 0; it < 2; ++it) {
      int id = t + it * 256;
      int r = id >> 2;
      int kq = (id & 3) * 4;
      float4 v = *(const float4*)&A[(long)(r0 + r) * din + (k0 + kq)];
      As[kq + 0][r] = v.x; As[kq + 1][r] = v.y;
      As[kq + 2][r] = v.z; As[kq + 3][r] = v.w;
      int k = id >> 5;
      int cq = (id & 31) * 4;
      float4 w = *(const float4*)&W[(long)(k0 + k) * dout + (c0 + cq)];
      *(float4*)&Ws[k][cq] = w;
    }
    __syncthreads();
#pragma unroll
    for (int k = 0; k < 16; ++k) {
      float av[8], bv[8];
      *(float4*)&av[0] = *(const float4*)&As[k][ty * 4];
      *(float4*)&av[4] = *(const float4*)&As[k][ty * 4 + 64];
      *(float4*)&bv[0] = *(const float4*)&Ws[k][tx * 4];
      *(float4*)&bv[4] = *(const float4*)&Ws[k][tx * 4 + 64];
#pragma unroll
      for (int i = 0; i < 8; ++i)
#pragma unroll
        for (int j = 0; j < 8; ++j)
          acc[i][j] = fmaf(av[i], bv[j], acc[i][j]);
    }
  }

  float bbv[8];
  *(float4*)&bbv[0] = *(const float4*)&bias[c0 + tx * 4];
  *(float4*)&bbv[4] = *(const float4*)&bias[c0 + tx * 4 + 64];
#pragma unroll
  for (int i = 0; i < 8; ++i) {
    long row = r0 + ty * 4 + (i & 3) + ((i >> 2) * 64);
    float o[8];
#pragma unroll
    for (int j = 0; j < 8; ++j) {
      float v = acc[i][j] + bbv[j];
      o[j] = GELU ? gelu_f(v) : v;
    }
    *(float4*)&C[row * dout + c0 + tx * 4] = *(float4*)&o[0];
    *(float4*)&C[row * dout + c0 + tx * 4 + 64] = *(float4*)&o[4];
  }
}

// ---------------- bf16x3-split MFMA GEMM (fp32-accurate) ----------------
// R10 structure; staging rewritten register-only (no punned local arrays).
template <bool GELU>
__global__ __launch_bounds__(256) void mfma3_gemm(
    const float* __restrict__ A, const unsigned short* __restrict__ Wt,
    size_t wpStride, const float* __restrict__ bias, float* __restrict__ C,
    int K, int dout) {
  __shared__ unsigned short A_s[3][128][40];
  __shared__ unsigned short B_s[3][128][40];
  int t = threadIdx.x;
  int lane = t & 63, wave = t >> 6;
  int q = lane >> 4, m = lane & 15;
  int wr = (wave >> 1) * 64, wc = (wave & 1) * 64;
  long r0 = (long)blockIdx.y * 128;
  int c0 = blockIdx.x * 128;

  f32x4 acc[4][4];
#pragma unroll
  for (int i = 0; i < 4; ++i)
#pragma unroll
    for (int j = 0; j < 4; ++j) acc[i][j] = (f32x4){0.f, 0.f, 0.f, 0.f};

  int rs = t >> 1, hs = (t & 1) * 16;
  const float* aptr = A + (r0 + rs) * K + hs;
  const unsigned short* bptr = Wt + (long)(c0 + rs) * K + hs;

  for (int kt = 0; kt < K; kt += 32) {
    __syncthreads();
    {
      float4 f0 = *(const float4*)(aptr + kt + 0);
      float4 f1 = *(const float4*)(aptr + kt + 4);
      float4 f2 = *(const float4*)(aptr + kt + 8);
      float4 f3 = *(const float4*)(aptr + kt + 12);
      uint4 L0, L1, L2, H0, H1, H2;
      split2pack(f0.x, f0.y, L0.x, L1.x, L2.x);
      split2pack(f0.z, f0.w, L0.y, L1.y, L2.y);
      split2pack(f1.x, f1.y, L0.z, L1.z, L2.z);
      split2pack(f1.z, f1.w, L0.w, L1.w, L2.w);
      split2pack(f2.x, f2.y, H0.x, H1.x, H2.x);
      split2pack(f2.z, f2.w, H0.y, H1.y, H2.y);
      split2pack(f3.x, f3.y, H0.z, H1.z, H2.z);
      split2pack(f3.z, f3.w, H0.w, H1.w, H2.w);
      *(uint4*)&A_s[0][rs][hs] = L0;
      *(uint4*)&A_s[0][rs][hs + 8] = H0;
      *(uint4*)&A_s[1][rs][hs] = L1;
      *(uint4*)&A_s[1][rs][hs + 8] = H1;
      *(uint4*)&A_s[2][rs][hs] = L2;
      *(uint4*)&A_s[2][rs][hs + 8] = H2;
#pragma unroll
      for (int p = 0; p < 3; ++p) {
        *(uint4*)&B_s[p][rs][hs] = *(const uint4*)(bptr + p * wpStride + kt);
        *(uint4*)&B_s[p][rs][hs + 8] =
            *(const uint4*)(bptr + p * wpStride + kt + 8);
      }
    }
    __syncthreads();
    short8 af[3][4];
#pragma unroll
    for (int p = 0; p < 3; ++p)
#pragma unroll
      for (int x = 0; x < 4; ++x)
        af[p][x] = *(const short8*)&A_s[p][wr + x * 16 + m][q * 8];
#pragma unroll
    for (int ct = 0; ct < 4; ++ct) {
      short8 b0 = *(const short8*)&B_s[0][wc + ct * 16 + m][q * 8];
      short8 b1 = *(const short8*)&B_s[1][wc + ct * 16 + m][q * 8];
      short8 b2 = *(const short8*)&B_s[2][wc + ct * 16 + m][q * 8];
#pragma unroll
      for (int rt = 0; rt < 4; ++rt) {
        acc[rt][ct] = mfma16(af[0][rt], b0, acc[rt][ct]);
        acc[rt][ct] = mfma16(af[0][rt], b1, acc[rt][ct]);
        acc[rt][ct] = mfma16(af[1][rt], b0, acc[rt][ct]);
        acc[rt][ct] = mfma16(af[1][rt], b1, acc[rt][ct]);
        acc[rt][ct] = mfma16(af[0][rt], b2, acc[rt][ct]);
        acc[rt][ct] = mfma16(af[2][rt], b0, acc[rt][ct]);
      }
    }
  }

#pragma unroll
  for (int ct = 0; ct < 4; ++ct) {
    long col = c0 + wc + ct * 16 + m;
    float bv = bias[col];
#pragma unroll
    for (int rt = 0; rt < 4; ++rt) {
      long rowb = r0 + wr + rt * 16 + q * 4;
#pragma unroll
      for (int r = 0; r < 4; ++r) {
        float v = acc[rt][ct][r] + bv;
        if (GELU) v = gelu_f(v);
        C[(rowb + r) * dout + col] = v;
      }
    }
  }
}

// ---------------- plain bf16 MFMA GEMM (decoder) ----------------
template <bool GELU, bool GATHER>
__global__ __launch_bounds__(256) void mfma_gemm(
    const unsigned short* __restrict__ A, const unsigned short* __restrict__ Wt,
    const float* __restrict__ bias, unsigned short* __restrict__ C,
    int K, int dout, const int* __restrict__ gidx) {
  __shared__ unsigned short A_s[128 * 72];
  __shared__ unsigned short B_s[128 * 72];
  int t = threadIdx.x;
  int lane = t & 63, wave = t >> 6;
  int q = lane >> 4, m = lane & 15;
  int wr = (wave >> 1) * 64, wc = (wave & 1) * 64;
  long r0 = (long)blockIdx.y * 128;
  int c0 = blockIdx.x * 128;

  f32x4 acc[4][4];
#pragma unroll
  for (int i = 0; i < 4; ++i)
#pragma unroll
    for (int j = 0; j < 4; ++j) acc[i][j] = (f32x4){0.f, 0.f, 0.f, 0.f};

  int rs = t >> 1, hs = (t & 1) * 32;
  long arow = GATHER ? (long)gidx[r0 + rs] : (r0 + rs);
  const unsigned short* aptr = A + arow * K + hs;
  const unsigned short* bptr = Wt + (long)(c0 + rs) * K + hs;

  for (int kt = 0; kt < K; kt += 64) {
    __syncthreads();
    {
      const uint4* ap = (const uint4*)(aptr + kt);
      const uint4* bp = (const uint4*)(bptr + kt);
      uint4* ad = (uint4*)&A_s[rs * 72 + hs];
      uint4* bd = (uint4*)&B_s[rs * 72 + hs];
#pragma unroll
      for (int i = 0; i < 4; ++i) { ad[i] = ap[i]; bd[i] = bp[i]; }
    }
    __syncthreads();
#pragma unroll
    for (int kc = 0; kc < 2; ++kc) {
      short8 af[4], bfr[4];
#pragma unroll
      for (int x = 0; x < 4; ++x) {
        af[x] = *(const short8*)&A_s[(wr + x * 16 + m) * 72 + kc * 32 + q * 8];
        bfr[x] = *(const short8*)&B_s[(wc + x * 16 + m) * 72 + kc * 32 + q * 8];
      }
#pragma unroll
      for (int rt = 0; rt < 4; ++rt)
#pragma unroll
        for (int ct = 0; ct < 4; ++ct)
          acc[rt][ct] = mfma16(af[rt], bfr[ct], acc[rt][ct]);
    }
  }

#pragma unroll
  for (int ct = 0; ct < 4; ++ct) {
    int col = c0 + wc + ct * 16 + m;
    float bv = bias[col];
#pragma unroll
    for (int rt = 0; rt < 4; ++rt) {
      long rowb = r0 + wr + rt * 16 + q * 4;
#pragma unroll
      for (int r = 0; r < 4; ++r) {
        float v = acc[rt][ct][r] + bv;
        if (GELU) v = gelu_f(v);
        C[(rowb + r) * dout + col] = f2bf(v);
      }
    }
  }
}

// ---------------- bf16 MFMA distances: top-2 of z_e . cb^T, flag near-ties ----------------
__global__ __launch_bounds__(256) void dist_mfma(
    const unsigned short* __restrict__ zeb, const unsigned short* __restrict__ cbb,
    int* __restrict__ idxc, int* __restrict__ fixcnt, int* __restrict__ fixlist) {
  __shared__ unsigned short A_s[128 * 72];
  __shared__ unsigned short B_s[128 * 72];
  __shared__ float Lv1[128][2], Lv2[128][2];
  __shared__ int Lc1[128][2];
  int t = threadIdx.x;
  int lane = t & 63, wave = t >> 6;
  int q = lane >> 4, m = lane & 15;
  int wr = (wave >> 1) * 64, wcb = wave & 1;
  int wc = wcb * 64;
  int r0 = blockIdx.x * 128;

  float v1[4][4], v2[4][4];
  int c1[4][4];
#pragma unroll
  for (int i = 0; i < 4; ++i)
#pragma unroll
    for (int j = 0; j < 4; ++j) { v1[i][j] = -3.4e38f; v2[i][j] = -3.4e38f; c1[i][j] = 0; }

  int rs = t >> 1, hs = (t & 1) * 32;
  const unsigned short* aptr = zeb + (long)(r0 + rs) * 256 + hs;

  for (int ct = 0; ct < 8; ++ct) {
    int c0 = ct * 128;
    const unsigned short* bptr = cbb + (long)(c0 + rs) * 256 + hs;
    f32x4 acc[4][4];
#pragma unroll
    for (int i = 0; i < 4; ++i)
#pragma unroll
      for (int j = 0; j < 4; ++j) acc[i][j] = (f32x4){0.f, 0.f, 0.f, 0.f};

    for (int kt = 0; kt < 256; kt += 64) {
      __syncthreads();
      {
        const uint4* ap = (const uint4*)(aptr + kt);
        const uint4* bp = (const uint4*)(bptr + kt);
        uint4* ad = (uint4*)&A_s[rs * 72 + hs];
        uint4* bd = (uint4*)&B_s[rs * 72 + hs];
#pragma unroll
        for (int i = 0; i < 4; ++i) { ad[i] = ap[i]; bd[i] = bp[i]; }
      }
      __syncthreads();
#pragma unroll
      for (int kc = 0; kc < 2; ++kc) {
        short8 af[4], bfr[4];
#pragma unroll
        for (int x = 0; x < 4; ++x) {
          af[x] = *(const short8*)&A_s[(wr + x * 16 + m) * 72 + kc * 32 + q * 8];
          bfr[x] = *(const short8*)&B_s[(wc + x * 16 + m) * 72 + kc * 32 + q * 8];
        }
#pragma unroll
        for (int rt = 0; rt < 4; ++rt)
#pragma unroll
          for (int c2 = 0; c2 < 4; ++c2)
            acc[rt][c2] = mfma16(af[rt], bfr[c2], acc[rt][c2]);
      }
    }
#pragma unroll
    for (int rt = 0; rt < 4; ++rt)
#pragma unroll
      for (int c2 = 0; c2 < 4; ++c2) {
        int colb = c0 + wc + c2 * 16 + m;
#pragma unroll
        for (int r = 0; r < 4; ++r) {
          float v = acc[rt][c2][r];
          float nv2 = fmaxf(v2[rt][r], fminf(v, v1[rt][r]));
          if (v > v1[rt][r]) { c1[rt][r] = colb; v1[rt][r] = v; }
          v2[rt][r] = nv2;
        }
      }
  }

#pragma unroll
  for (int off = 1; off <= 8; off <<= 1) {
#pragma unroll
    for (int rt = 0; rt < 4; ++rt)
#pragma unroll
      for (int r = 0; r < 4; ++r) {
        float ov1 = __shfl_xor(v1[rt][r], off);
        float ov2 = __shfl_xor(v2[rt][r], off);
        int oc1 = __shfl_xor(c1[rt][r], off);
        float nv2 = fmaxf(fmaxf(v2[rt][r], ov2), fminf(v1[rt][r], ov1));
        if (ov1 > v1[rt][r] || (ov1 == v1[rt][r] && oc1 < c1[rt][r])) {
          v1[rt][r] = ov1; c1[rt][r] = oc1;
        }
        v2[rt][r] = nv2;
      }
  }
  if (m == 0) {
#pragma unroll
    for (int rt = 0; rt < 4; ++rt)
#pragma unroll
      for (int r = 0; r < 4; ++r) {
        int rloc = wr + rt * 16 + q * 4 + r;
        Lv1[rloc][wcb] = v1[rt][r];
        Lv2[rloc][wcb] = v2[rt][r];
        Lc1[rloc][wcb] = c1[rt][r];
      }
  }
  __syncthreads();
  if (t < 128) {
    float a1 = Lv1[t][0], a2 = Lv2[t][0];
    int ac = Lc1[t][0];
    float b1 = Lv1[t][1], b2 = Lv2[t][1];
    int bc = Lc1[t][1];
    float m2 = fmaxf(fmaxf(a2, b2), fminf(a1, b1));
    float m1; int mc;
    if (b1 > a1 || (b1 == a1 && bc < ac)) { m1 = b1; mc = bc; }
    else { m1 = a1; mc = ac; }
    idxc[r0 + t] = mc;
    if (m1 - m2 < 0.005f) {
      int p = atomicAdd(fixcnt, 1);
      fixlist[p] = r0 + t;
    }
  }
}

// ---------------- fp32 exact argmin fixup, code-parallel ----------------
__global__ __launch_bounds__(256) void fixup_part(
    const float* __restrict__ z_e, const float* __restrict__ cbn,
    const float* __restrict__ ze2, const float* __restrict__ cb2,
    const int* __restrict__ fixlist, const int* __restrict__ fixcnt,
    float* __restrict__ fixbv, int* __restrict__ fixbc) {
  int cnt = *fixcnt;
  int r0 = blockIdx.y * 128;
  if (r0 >= cnt) return;
  int ctile = blockIdx.x;
  int c0 = ctile * 128;
  __shared__ float As[16][132];
  __shared__ float Ws[16][132];
  __shared__ float rv[128][17];
  __shared__ int rc[128][17];
  __shared__ int rows_l[128];
  int t = threadIdx.x, tx = t & 15, ty = t >> 4;

  if (t < 128) rows_l[t] = fixlist[(r0 + t < cnt) ? (r0 + t) : 0];
  __syncthreads();

  float bestv[8];
  int bestc[8];
  float myze2[8];
#pragma unroll
  for (int i = 0; i < 8; ++i) {
    bestv[i] = 3.4e38f;
    bestc[i] = 0;
    int rl = ty * 4 + (i & 3) + ((i >> 2) * 64);
    myze2[i] = ze2[rows_l[rl]];
  }

  float acc[8][8];
#pragma unroll
  for (int i = 0; i < 8; ++i)
#pragma unroll
    for (int j = 0; j < 8; ++j) acc[i][j] = 0.0f;

  for (int kc = 0; kc < 16; ++kc) {
    int k0 = kc << 4;
    __syncthreads();
#pragma unroll
    for (int it = 0; it < 2; ++it) {
      int id = t + it * 256;
      int r = id >> 2;
      int kq = (id & 3) * 4;
      float4 v = *(const float4*)&z_e[(long)rows_l[r] * 256 + k0 + kq];
      As[kq + 0][r] = v.x; As[kq + 1][r] = v.y;
      As[kq + 2][r] = v.z; As[kq + 3][r] = v.w;
      float4 w = *(const float4*)&cbn[(long)(c0 + r) * 256 + k0 + kq];
      Ws[kq + 0][r] = w.x; Ws[kq + 1][r] = w.y;
      Ws[kq + 2][r] = w.z; Ws[kq + 3][r] = w.w;
    }
    __syncthreads();
#pragma unroll
    for (int k = 0; k < 16; ++k) {
      float av[8], bv[8];
      *(float4*)&av[0] = *(const float4*)&As[k][ty * 4];
      *(float4*)&av[4] = *(const float4*)&As[k][ty * 4 + 64];
      *(float4*)&bv[0] = *(const float4*)&Ws[k][tx * 4];
      *(float4*)&bv[4] = *(const float4*)&Ws[k][tx * 4 + 64];
#pragma unroll
      for (int i = 0; i < 8; ++i)
#pragma unroll
        for (int j = 0; j < 8; ++j)
          acc[i][j] = fmaf(av[i], bv[j], acc[i][j]);
    }
  }

  float cb2v[8];
  *(float4*)&cb2v[0] = *(const float4*)&cb2[c0 + tx * 4];
  *(float4*)&cb2v[4] = *(const float4*)&cb2[c0 + tx * 4 + 64];
#pragma unroll
  for (int i = 0; i < 8; ++i)
#pragma unroll
    for (int j = 0; j < 8; ++j) {
      int c = c0 + tx * 4 + (j & 3) + ((j >> 2) * 64);
      float d = (myze2[i] - 2.0f * acc[i][j]) + cb2v[j];
      if (d < bestv[i] || (d == bestv[i] && c < bestc[i])) {
        bestv[i] = d;
        bestc[i] = c;
      }
    }

  __syncthreads();
#pragma unroll
  for (int i = 0; i < 8; ++i) {
    int rl = ty * 4 + (i & 3) + ((i >> 2) * 64);
    rv[rl][tx] = bestv[i];
    rc[rl][tx] = bestc[i];
  }
  __syncthreads();
  if (t < 128 && r0 + t < cnt) {
    float bv = rv[t][0];
    int bc = rc[t][0];
    for (int j = 1; j < 16; ++j) {
      float v = rv[t][j];
      int c = rc[t][j];
      if (v < bv || (v == bv && c < bc)) { bv = v; bc = c; }
    }
    fixbv[(long)(r0 + t) * 8 + ctile] = bv;
    fixbc[(long)(r0 + t) * 8 + ctile] = bc;
  }
}

__global__ __launch_bounds__(256) void fixup_reduce(
    const float* __restrict__ fixbv, const int* __restrict__ fixbc,
    const int* __restrict__ fixlist, const int* __restrict__ fixcnt,
    int* __restrict__ idxc) {
  int cnt = *fixcnt;
  int i = blockIdx.x * 256 + threadIdx.x;
  if (i >= cnt) return;
  float bv = fixbv[(long)i * 8];
  int bc = fixbc[(long)i * 8];
#pragma unroll
  for (int j = 1; j < 8; ++j) {
    float v = fixbv[(long)i * 8 + j];
    int c = fixbc[(long)i * 8 + j];
    if (v < bv || (v == bv && c < bc)) { bv = v; bc = c; }
  }
  idxc[fixlist[i]] = bc;
}

// ---------------- row L2 normalize -> fp32 + bf16 + sumsq ----------------
__global__ __launch_bounds__(256) void rownorm_kernel(
    const float* __restrict__ in, float* __restrict__ outv,
    unsigned short* __restrict__ outb, float* __restrict__ outsq) {
  int wid = threadIdx.x >> 6, lane = threadIdx.x & 63;
  long row = (long)blockIdx.x * 4 + wid;
  const float* src = in + row * 256;
  float4 v = *(const float4*)&src[lane * 4];
  float s = v.x * v.x + v.y * v.y + v.z * v.z + v.w * v.w;
#pragma unroll
  for (int off = 32; off >= 1; off >>= 1) s += __shfl_xor(s, off);
  float denom = sqrtf(s) + 1e-8f;
  float4 o;
  o.x = v.x / denom; o.y = v.y / denom; o.z = v.z / denom; o.w = v.w / denom;
  *(float4*)&outv[row * 256 + lane * 4] = o;
  ushort4 ob;
  ob.x = f2bf(o.x); ob.y = f2bf(o.y); ob.z = f2bf(o.z); ob.w = f2bf(o.w);
  *(ushort4*)&outb[row * 256 + lane * 4] = ob;
  float s2 = o.x * o.x + o.y * o.y + o.z * o.z + o.w * o.w;
#pragma unroll
  for (int off = 32; off >= 1; off >>= 1) s2 += __shfl_xor(s2, off);
  if (lane == 0) outsq[row] = s2;
}

// ---------------- W [K][N] fp32 -> Wt [N][K] bf16 (single plane) ----------------
__global__ __launch_bounds__(256) void transpose_w_kernel(
    const float* __restrict__ W, unsigned short* __restrict__ Wt, int K, int N) {
  __shared__ float tile[32][33];
  int n0 = blockIdx.x * 32, k0 = blockIdx.y * 32;
  int tx = threadIdx.x & 31, ty = threadIdx.x >> 5;
#pragma unroll
  for (int i = 0; i < 32; i += 8)
    tile[ty + i][tx] = W[(long)(k0 + ty + i) * N + n0 + tx];
  __syncthreads();
#pragma unroll
  for (int i = 0; i < 32; i += 8)
    Wt[(long)(n0 + ty + i) * K + k0 + tx] = f2bf(tile[tx][ty + i]);
}

// ---------------- W [K][N] fp32 -> 3 bf16 planes Wt_p [N][K] ----------------
__global__ __launch_bounds__(256) void split_transpose_kernel(
    const float* __restrict__ W, unsigned short* __restrict__ Wt, size_t ps,
    int K, int N) {
  __shared__ float tile[32][33];
  int n0 = blockIdx.x * 32, k0 = blockIdx.y * 32;
  int tx = threadIdx.x & 31, ty = threadIdx.x >> 5;
#pragma unroll
  for (int i = 0; i < 32; i += 8)
    tile[ty + i][tx] = W[(long)(k0 + ty + i) * N + n0 + tx];
  __syncthreads();
#pragma unroll
  for (int i = 0; i < 32; i += 8) {
    unsigned short p0, p1, p2;
    split3(tile[tx][ty + i], p0, p1, p2);
    long o = (long)(n0 + ty + i) * K + k0 + tx;
    Wt[0 * ps + o] = p0;
    Wt[1 * ps + o] = p1;
    Wt[2 * ps + o] = p2;
  }
}

// ---------------- decoder last layer (bf16 in, dout=32) + recon loss ----------------
__global__ __launch_bounds__(256) void dec2_kernel(
    const unsigned short* __restrict__ D1, const float* __restrict__ W,
    const float* __restrict__ bias, const float* __restrict__ action,
    const float* __restrict__ dimw, float* __restrict__ ahat,
    float* __restrict__ accum) {
  __shared__ float As[16][66];
  __shared__ float Ws[16][32];
  int t = threadIdx.x, tx = t & 7, ty = t >> 3;
  int r0 = blockIdx.x * 64;
  float acc[2][4] = {{0, 0, 0, 0}, {0, 0, 0, 0}};

  for (int kc = 0; kc < 32; ++kc) {
    int k0 = kc << 4;
    __syncthreads();
    {
      int r = t >> 2, kq = (t & 3) * 4;
      ushort4 u = *(const ushort4*)&D1[(long)(r0 + r) * 512 + k0 + kq];
      As[kq + 0][r] = bf2f(u.x); As[kq + 1][r] = bf2f(u.y);
      As[kq + 2][r] = bf2f(u.z); As[kq + 3][r] = bf2f(u.w);
      if (t < 128) {
        int k = t >> 3, cq = (t & 7) * 4;
        *(float4*)&Ws[k][cq] = *(const float4*)&W[(long)(k0 + k) * 32 + cq];
      }
    }
    __syncthreads();
#pragma unroll
    for (int k = 0; k < 16; ++k) {
      float2 a = *(const float2*)&As[k][ty * 2];
      float4 b = *(const float4*)&Ws[k][tx * 4];
      acc[0][0] = fmaf(a.x, b.x, acc[0][0]);
      acc[0][1] = fmaf(a.x, b.y, acc[0][1]);
      acc[0][2] = fmaf(a.x, b.z, acc[0][2]);
      acc[0][3] = fmaf(a.x, b.w, acc[0][3]);
      acc[1][0] = fmaf(a.y, b.x, acc[1][0]);
      acc[1][1] = fmaf(a.y, b.y, acc[1][1]);
      acc[1][2] = fmaf(a.y, b.z, acc[1][2]);
      acc[1][3] = fmaf(a.y, b.w, acc[1][3]);
    }
  }

  float4 bb = *(const float4*)&bias[tx * 4];
  float4 dw = *(const float4*)&dimw[tx * 4];
  float lsum = 0.0f;
#pragma unroll
  for (int rr = 0; rr < 2; ++rr) {
    long row = r0 + ty * 2 + rr;
    float4 av = *(const float4*)&action[row * 32 + tx * 4];
    float4 o;
    o.x = acc[rr][0] + bb.x; o.y = acc[rr][1] + bb.y;
    o.z = acc[rr][2] + bb.z; o.w = acc[rr][3] + bb.w;
    *(float4*)&ahat[row * 32 + tx * 4] = o;
    float ex = av.x - o.x, ey = av.y - o.y, ez = av.z - o.z, ew = av.w - o.w;
    lsum += ex * ex * dw.x + ey * ey * dw.y + ez * ez * dw.z + ew * ew * dw.w;
  }
#pragma unroll
  for (int off = 32; off >= 1; off >>= 1) lsum += __shfl_xor(lsum, off);
  __shared__ float red[4];
  int wid = t >> 6, lane = t & 63;
  if (lane == 0) red[wid] = lsum;
  __syncthreads();
  if (t == 0) atomicAdd(accum, red[0] + red[1] + red[2] + red[3]);
}

// ---------------- commit loss + idx->float (fused) ----------------
__global__ __launch_bounds__(256) void commit_idx_kernel(
    const float* __restrict__ z_e, const float* __restrict__ cbn,
    const int* __restrict__ idx, float* __restrict__ accum,
    float* __restrict__ outIdx) {
  int wid = threadIdx.x >> 6, lane = threadIdx.x & 63;
  long row = (long)blockIdx.x * 4 + wid;
  int k = idx[row];
  float4 a = *(const float4*)&z_e[row * 256 + lane * 4];
  float4 b = *(const float4*)&cbn[(long)k * 256 + lane * 4];
  float dx = a.x - b.x, dy = a.y - b.y, dz = a.z - b.z, dw = a.w - b.w;
  float s = dx * dx + dy * dy + dz * dz + dw * dw;
#pragma unroll
  for (int off = 32; off >= 1; off >>= 1) s += __shfl_xor(s, off);
  __shared__ float red[4];
  if (lane == 0) {
    red[wid] = s;
    outIdx[row] = (float)k;
  }
  __syncthreads();
  if (threadIdx.x == 0) atomicAdd(accum, red[0] + red[1] + red[2] + red[3]);
}

__global__ void zero_kernel(float* __restrict__ acc, int* __restrict__ cnts) {
  if (threadIdx.x < 2) acc[threadIdx.x] = 0.0f;
  if (threadIdx.x < 32) cnts[threadIdx.x] = 0;
}

__global__ void finalize_kernel(const float* __restrict__ acc,
                                float* __restrict__ out) {
  out[0] = acc[0] / (65536.0f * 32.0f);
  float cl = acc[1] / (65536.0f * 256.0f);
  out[1] = cl;
  out[2] = cl;
}

extern "C" void kernel_launch(void* const* d_in, const int* in_sizes, int n_in,
                              void* d_out, int out_size, void* d_ws,
                              size_t ws_size, hipStream_t stream) {
  const float* action = (const float*)d_in[0];
  const float* dimw = (const float*)d_in[1];
  const float* ew0 = (const float*)d_in[2];
  const float* eb0 = (const float*)d_in[3];
  const float* ew1 = (const float*)d_in[4];
  const float* eb1 = (const float*)d_in[5];
  const float* ew2 = (const float*)d_in[6];
  const float* eb2 = (const float*)d_in[7];
  const float* dw0 = (const float*)d_in[8];
  const float* db0 = (const float*)d_in[9];
  const float* dw1 = (const float*)d_in[10];
  const float* db1 = (const float*)d_in[11];
  const float* dw2 = (const float*)d_in[12];
  const float* db2 = (const float*)d_in[13];
  const float* cb = (const float*)d_in[14];
  float* out = (float*)d_out;
  char* ws = (char*)d_ws;

  // fixed region
  const size_t fixed_b = 1048576 + 4096 + 524288 + 524288 + 1048576 +
                         3145728 + 1572864 + 256;
  // per-row: P0 2560 + P1 4096 + ze2 4 + idxc 4 + fixlist 4 + partials 64
  int R = N_ROWS;
  while (R > 2048) {
    if (fixed_b + (size_t)R * 6732 + 65536 <= ws_size) break;
    R >>= 1;
  }

  size_t off = 0;
  float* cbn = (float*)(ws + off); off += 1048576;
  float* cb2 = (float*)(ws + off); off += 4096;
  unsigned short* cbb = (unsigned short*)(ws + off); off += 524288;
  unsigned short* dwt0 = (unsigned short*)(ws + off); off += 524288;
  unsigned short* dwt1 = (unsigned short*)(ws + off); off += 1048576;
  unsigned short* ewt1p = (unsigned short*)(ws + off); off += 3145728;  // 3 x 1024x512
  unsigned short* ewt2p = (unsigned short*)(ws + off); off += 1572864;  // 3 x 256x1024
  float* accum = (float*)(ws + off);
  int* fixcnts = (int*)(ws + off + 64); off += 256;
  float* ze2 = (float*)(ws + off); off += (size_t)R * 4;
  int* idxc = (int*)(ws + off); off += (size_t)R * 4;
  int* fixlist = (int*)(ws + off); off += (size_t)R * 4;
  float* fixbv = (float*)(ws + off); off += (size_t)R * 32;
  int* fixbc = (int*)(ws + off); off += (size_t)R * 32;
  char* P0 = ws + off; off += (size_t)R * 2560;
  char* P1 = ws + off; off += (size_t)R * 4096;

  float* e0 = (float*)P0;                         // R x 512 f32 (first 2048 B/row)
  float* e1 = (float*)P1;                         // R x 1024 f32
  float* zbuf = (float*)P0;                       // R x 256 f32
  float* z_e = (float*)(P0 + (size_t)R * 1024);   // R x 256 f32
  unsigned short* zeb = (unsigned short*)(P0 + (size_t)R * 2048);  // R x 256 bf16
  unsigned short* D0b = (unsigned short*)P1;                       // R x 1024 bf16
  unsigned short* D1b = (unsigned short*)(P1 + (size_t)R * 2048);  // R x 512 bf16

  zero_kernel<<<1, 64, 0, stream>>>(accum, fixcnts);
  rownorm_kernel<<<256, 256, 0, stream>>>(cb, cbn, cbb, cb2);
  transpose_w_kernel<<<dim3(32, 8), 256, 0, stream>>>(dw0, dwt0, 256, 1024);
  transpose_w_kernel<<<dim3(16, 32), 256, 0, stream>>>(dw1, dwt1, 1024, 512);
  split_transpose_kernel<<<dim3(32, 16), 256, 0, stream>>>(
      ew1, ewt1p, (size_t)1024 * 512, 512, 1024);
  split_transpose_kernel<<<dim3(8, 32), 256, 0, stream>>>(
      ew2, ewt2p, (size_t)256 * 1024, 1024, 256);

  for (int base = 0; base < N_ROWS; base += R) {
    int ci = base / R;
    const float* act_c = action + (size_t)base * 32;
    float* out_c = out + (size_t)base * 32;
    int* fixcnt = &fixcnts[ci];

    // encoder: e0 (fp32) -> P0, e1 (bf16x3 MFMA) -> P1, z -> P0
    gemm_kernel<true><<<dim3(4, R / 128), 256, 0, stream>>>(
        act_c, ew0, eb0, e0, 32, 512);
    mfma3_gemm<true><<<dim3(8, R / 128), 256, 0, stream>>>(
        e0, ewt1p, (size_t)1024 * 512, eb1, e1, 512, 1024);
    mfma3_gemm<false><<<dim3(2, R / 128), 256, 0, stream>>>(
        e1, ewt2p, (size_t)256 * 1024, eb2, zbuf, 1024, 256);

    rownorm_kernel<<<R / 4, 256, 0, stream>>>(zbuf, z_e, zeb, ze2);

    dist_mfma<<<R / 128, 256, 0, stream>>>(zeb, cbb, idxc, fixcnt, fixlist);
    fixup_part<<<dim3(8, R / 128), 256, 0, stream>>>(
        z_e, cbn, ze2, cb2, fixlist, fixcnt, fixbv, fixbc);
    fixup_reduce<<<R / 256, 256, 0, stream>>>(fixbv, fixbc, fixlist, fixcnt,
                                              idxc);

    commit_idx_kernel<<<R / 4, 256, 0, stream>>>(z_e, cbn, idxc, &accum[1],
                                                 out + 2097152 + base);

    // decoder: d0 -> D0b (e1 dead), d1 -> D1b, dec2 + recon loss
    mfma_gemm<true, true><<<dim3(8, R / 128), 256, 0, stream>>>(
        cbb, dwt0, db0, D0b, 256, 1024, idxc);
    mfma_gemm<true, false><<<dim3(4, R / 128), 256, 0, stream>>>(
        D0b, dwt1, db1, D1b, 1024, 512, nullptr);
    dec2_kernel<<<R / 64, 256, 0, stream>>>(D1b, dw2, db2, act_c, dimw, out_c,
                                            &accum[0]);
  }

  finalize_kernel<<<1, 1, 0, stream>>>(accum, out + 2162688);
}

// Round 12
// 1567.563 us; speedup vs baseline: 1.0556x; 1.0556x over previous
//
#include <hip/hip_runtime.h>
#include <math.h>

#define N_ROWS 65536

typedef short short8 __attribute__((ext_vector_type(8)));
typedef float f32x4 __attribute__((ext_vector_type(4)));

__device__ __forceinline__ float gelu_f(float x) {
  float x3 = x * x * x;
  float t = tanhf(0.7978845608028654f * (x + 0.044715f * x3));
  return 0.5f * x * (1.0f + t);
}

__device__ __forceinline__ unsigned short f2bf(float f) {
  unsigned u = __float_as_uint(f);
  unsigned r = u + 0x7fffu + ((u >> 16) & 1u);
  return (unsigned short)(r >> 16);
}
__device__ __forceinline__ float bf2f(unsigned short h) {
  return __uint_as_float(((unsigned)h) << 16);
}

// RNE split (one-time weight prep)
__device__ __forceinline__ void split3(float v, unsigned short& p0,
                                       unsigned short& p1, unsigned short& p2) {
  p0 = f2bf(v);
  float r = v - bf2f(p0);
  p1 = f2bf(r);
  r -= bf2f(p1);
  p2 = f2bf(r);
}

// cheap split: round-half-up planes 0/1 (<=0.5 ulp, exact residuals), RNE last
__device__ __forceinline__ void split3f(float v, unsigned short& p0,
                                        unsigned short& p1, unsigned short& p2) {
  unsigned u = __float_as_uint(v);
  unsigned h0 = (u + 0x8000u) & 0xffff0000u;
  float r = v - __uint_as_float(h0);
  unsigned u1 = __float_as_uint(r);
  unsigned h1 = (u1 + 0x8000u) & 0xffff0000u;
  float r2 = r - __uint_as_float(h1);
  p0 = (unsigned short)(h0 >> 16);
  p1 = (unsigned short)(h1 >> 16);
  p2 = f2bf(r2);
}

__device__ __forceinline__ f32x4 mfma16(short8 a, short8 b, f32x4 c) {
  return __builtin_amdgcn_mfma_f32_16x16x32_bf16(a, b, c, 0, 0, 0);
}

// ---------------- fp32 GEMM (enc0): C = gelu(A @ W + b) ----------------
template <bool GELU>
__global__ __launch_bounds__(256) void gemm_kernel(
    const float* __restrict__ A, const float* __restrict__ W,
    const float* __restrict__ bias, float* __restrict__ C,
    int din, int dout) {
  __shared__ float As[16][132];
  __shared__ float Ws[16][132];
  int t = threadIdx.x;
  int tx = t & 15, ty = t >> 4;
  int c0 = blockIdx.x * 128;
  int r0 = blockIdx.y * 128;

  float acc[8][8];
#pragma unroll
  for (int i = 0; i < 8; ++i)
#pragma unroll
    for (int j = 0; j < 8; ++j) acc[i][j] = 0.0f;

  int kchunks = din >> 4;
  for (int kc = 0; kc < kchunks; ++kc) {
    int k0 = kc << 4;
    __syncthreads();
#pragma unroll
    for (int it = 0; it < 2; ++it) {
      int id = t + it * 256;
      int r = id >> 2;
      int kq = (id & 3) * 4;
      float4 v = *(const float4*)&A[(long)(r0 + r) * din + (k0 + kq)];
      As[kq + 0][r] = v.x; As[kq + 1][r] = v.y;
      As[kq + 2][r] = v.z; As[kq + 3][r] = v.w;
      int k = id >> 5;
      int cq = (id & 31) * 4;
      float4 w = *(const float4*)&W[(long)(k0 + k) * dout + (c0 + cq)];
      *(float4*)&Ws[k][cq] = w;
    }
    __syncthreads();
#pragma unroll
    for (int k = 0; k < 16; ++k) {
      float av[8], bv[8];
      *(float4*)&av[0] = *(const float4*)&As[k][ty * 4];
      *(float4*)&av[4] = *(const float4*)&As[k][ty * 4 + 64];
      *(float4*)&bv[0] = *(const float4*)&Ws[k][tx * 4];
      *(float4*)&bv[4] = *(const float4*)&Ws[k][tx * 4 + 64];
#pragma unroll
      for (int i = 0; i < 8; ++i)
#pragma unroll
        for (int j = 0; j < 8; ++j)
          acc[i][j] = fmaf(av[i], bv[j], acc[i][j]);
    }
  }

  float bbv[8];
  *(float4*)&bbv[0] = *(const float4*)&bias[c0 + tx * 4];
  *(float4*)&bbv[4] = *(const float4*)&bias[c0 + tx * 4 + 64];
#pragma unroll
  for (int i = 0; i < 8; ++i) {
    long row = r0 + ty * 4 + (i & 3) + ((i >> 2) * 64);
    float o[8];
#pragma unroll
    for (int j = 0; j < 8; ++j) {
      float v = acc[i][j] + bbv[j];
      o[j] = GELU ? gelu_f(v) : v;
    }
    *(float4*)&C[row * dout + c0 + tx * 4] = *(float4*)&o[0];
    *(float4*)&C[row * dout + c0 + tx * 4 + 64] = *(float4*)&o[4];
  }
}

// ---- W [K][N] fp32 -> 3-plane MFMA-fragment-major Bfrag ----
// layout: [colblk=N/16][kblk=K/32][plane 3][lane 64][8 shorts]
// fragment for (cb,kb,p), lane l=(q<<4)|m: Wt plane p of
// W[kb*32 + q*8 + j][cb*16 + m], j=0..7
__global__ void frag_pack_kernel(const float* __restrict__ W,
                                 unsigned short* __restrict__ Bf,
                                 int K, int N) {
  int l = threadIdx.x;
  int m = l & 15, q = l >> 4;
  int cb = blockIdx.x, kb = blockIdx.y;
  unsigned short s0[8], s1[8], s2[8];
#pragma unroll
  for (int j = 0; j < 8; ++j) {
    float v = W[(long)(kb * 32 + q * 8 + j) * N + cb * 16 + m];
    split3(v, s0[j], s1[j], s2[j]);
  }
  size_t base = ((size_t)cb * (K / 32) + kb) * 3 * 512;
  *(short8*)&Bf[base + 0 * 512 + l * 8] = *(short8*)s0;
  *(short8*)&Bf[base + 1 * 512 + l * 8] = *(short8*)s1;
  *(short8*)&Bf[base + 2 * 512 + l * 8] = *(short8*)s2;
}

// ---------------- bf16x3-split MFMA GEMM (fp32-accurate) ----------------
// A split to 3 bf16 planes on the fly in LDS (A-only LDS: 30.7 KB -> 5 blk/CU);
// B read per-fragment from global (coalesced dwordx4, L2-resident).
template <bool GELU>
__global__ __launch_bounds__(256) void mfma3_gemm(
    const float* __restrict__ A, const unsigned short* __restrict__ Bf,
    const float* __restrict__ bias, float* __restrict__ C,
    int K, int dout) {
  __shared__ unsigned short A_s[3][128][40];
  int t = threadIdx.x;
  int lane = t & 63, wave = t >> 6;
  int q = lane >> 4, m = lane & 15;
  int wr = (wave >> 1) * 64, wc = (wave & 1) * 64;
  long r0 = (long)blockIdx.y * 128;
  int c0 = blockIdx.x * 128;
  int kchunks = K >> 5;

  f32x4 acc[4][4];
#pragma unroll
  for (int i = 0; i < 4; ++i)
#pragma unroll
    for (int j = 0; j < 4; ++j) acc[i][j] = (f32x4){0.f, 0.f, 0.f, 0.f};

  int rs = t >> 1, hs = (t & 1) * 16;
  const float* aptr = A + (r0 + rs) * K + hs;
  // column-block base for this wave: (c0 + wc)/16
  int cb0 = (c0 + wc) >> 4;

  for (int kb = 0; kb < kchunks; ++kb) {
    __syncthreads();
    {
      int kt = kb << 5;
      float fv[16];
      *(float4*)&fv[0] = *(const float4*)(aptr + kt + 0);
      *(float4*)&fv[4] = *(const float4*)(aptr + kt + 4);
      *(float4*)&fv[8] = *(const float4*)(aptr + kt + 8);
      *(float4*)&fv[12] = *(const float4*)(aptr + kt + 12);
      unsigned short a0[16], a1[16], a2[16];
#pragma unroll
      for (int i = 0; i < 16; ++i) split3f(fv[i], a0[i], a1[i], a2[i]);
      *(uint4*)&A_s[0][rs][hs] = ((uint4*)a0)[0];
      *(uint4*)&A_s[0][rs][hs + 8] = ((uint4*)a0)[1];
      *(uint4*)&A_s[1][rs][hs] = ((uint4*)a1)[0];
      *(uint4*)&A_s[1][rs][hs + 8] = ((uint4*)a1)[1];
      *(uint4*)&A_s[2][rs][hs] = ((uint4*)a2)[0];
      *(uint4*)&A_s[2][rs][hs + 8] = ((uint4*)a2)[1];
    }
    __syncthreads();
    short8 af[3][4];
#pragma unroll
    for (int p = 0; p < 3; ++p)
#pragma unroll
      for (int x = 0; x < 4; ++x)
        af[p][x] = *(const short8*)&A_s[p][wr + x * 16 + m][q * 8];
#pragma unroll
    for (int ct = 0; ct < 4; ++ct) {
      size_t fb = ((size_t)(cb0 + ct) * kchunks + kb) * 3 * 512 + lane * 8;
      short8 b0 = *(const short8*)&Bf[fb];
      short8 b1 = *(const short8*)&Bf[fb + 512];
      short8 b2 = *(const short8*)&Bf[fb + 1024];
#pragma unroll
      for (int rt = 0; rt < 4; ++rt) {
        acc[rt][ct] = mfma16(af[0][rt], b0, acc[rt][ct]);
        acc[rt][ct] = mfma16(af[0][rt], b1, acc[rt][ct]);
        acc[rt][ct] = mfma16(af[1][rt], b0, acc[rt][ct]);
        acc[rt][ct] = mfma16(af[1][rt], b1, acc[rt][ct]);
        acc[rt][ct] = mfma16(af[0][rt], b2, acc[rt][ct]);
        acc[rt][ct] = mfma16(af[2][rt], b0, acc[rt][ct]);
      }
    }
  }

#pragma unroll
  for (int ct = 0; ct < 4; ++ct) {
    long col = c0 + wc + ct * 16 + m;
    float bv = bias[col];
#pragma unroll
    for (int rt = 0; rt < 4; ++rt) {
      long rowb = r0 + wr + rt * 16 + q * 4;
#pragma unroll
      for (int r = 0; r < 4; ++r) {
        float v = acc[rt][ct][r] + bv;
        if (GELU) v = gelu_f(v);
        C[(rowb + r) * dout + col] = v;
      }
    }
  }
}

// ---------------- plain bf16 MFMA GEMM (decoder) ----------------
template <bool GELU, bool GATHER>
__global__ __launch_bounds__(256) void mfma_gemm(
    const unsigned short* __restrict__ A, const unsigned short* __restrict__ Wt,
    const float* __restrict__ bias, unsigned short* __restrict__ C,
    int K, int dout, const int* __restrict__ gidx) {
  __shared__ unsigned short A_s[128 * 72];
  __shared__ unsigned short B_s[128 * 72];
  int t = threadIdx.x;
  int lane = t & 63, wave = t >> 6;
  int q = lane >> 4, m = lane & 15;
  int wr = (wave >> 1) * 64, wc = (wave & 1) * 64;
  long r0 = (long)blockIdx.y * 128;
  int c0 = blockIdx.x * 128;

  f32x4 acc[4][4];
#pragma unroll
  for (int i = 0; i < 4; ++i)
#pragma unroll
    for (int j = 0; j < 4; ++j) acc[i][j] = (f32x4){0.f, 0.f, 0.f, 0.f};

  int rs = t >> 1, hs = (t & 1) * 32;
  long arow = GATHER ? (long)gidx[r0 + rs] : (r0 + rs);
  const unsigned short* aptr = A + arow * K + hs;
  const unsigned short* bptr = Wt + (long)(c0 + rs) * K + hs;

  for (int kt = 0; kt < K; kt += 64) {
    __syncthreads();
    {
      const uint4* ap = (const uint4*)(aptr + kt);
      const uint4* bp = (const uint4*)(bptr + kt);
      uint4* ad = (uint4*)&A_s[rs * 72 + hs];
      uint4* bd = (uint4*)&B_s[rs * 72 + hs];
#pragma unroll
      for (int i = 0; i < 4; ++i) { ad[i] = ap[i]; bd[i] = bp[i]; }
    }
    __syncthreads();
#pragma unroll
    for (int kc = 0; kc < 2; ++kc) {
      short8 af[4], bfr[4];
#pragma unroll
      for (int x = 0; x < 4; ++x) {
        af[x] = *(const short8*)&A_s[(wr + x * 16 + m) * 72 + kc * 32 + q * 8];
        bfr[x] = *(const short8*)&B_s[(wc + x * 16 + m) * 72 + kc * 32 + q * 8];
      }
#pragma unroll
      for (int rt = 0; rt < 4; ++rt)
#pragma unroll
        for (int ct = 0; ct < 4; ++ct)
          acc[rt][ct] = mfma16(af[rt], bfr[ct], acc[rt][ct]);
    }
  }

#pragma unroll
  for (int ct = 0; ct < 4; ++ct) {
    int col = c0 + wc + ct * 16 + m;
    float bv = bias[col];
#pragma unroll
    for (int rt = 0; rt < 4; ++rt) {
      long rowb = r0 + wr + rt * 16 + q * 4;
#pragma unroll
      for (int r = 0; r < 4; ++r) {
        float v = acc[rt][ct][r] + bv;
        if (GELU) v = gelu_f(v);
        C[(rowb + r) * dout + col] = f2bf(v);
      }
    }
  }
}

// ---------------- bf16 MFMA distances: top-2 of z_e . cb^T, flag near-ties ----------------
__global__ __launch_bounds__(256) void dist_mfma(
    const unsigned short* __restrict__ zeb, const unsigned short* __restrict__ cbb,
    int* __restrict__ idxc, int* __restrict__ fixcnt, int* __restrict__ fixlist) {
  __shared__ unsigned short A_s[128 * 72];
  __shared__ unsigned short B_s[128 * 72];
  __shared__ float Lv1[128][2], Lv2[128][2];
  __shared__ int Lc1[128][2];
  int t = threadIdx.x;
  int lane = t & 63, wave = t >> 6;
  int q = lane >> 4, m = lane & 15;
  int wr = (wave >> 1) * 64, wcb = wave & 1;
  int wc = wcb * 64;
  int r0 = blockIdx.x * 128;

  float v1[4][4], v2[4][4];
  int c1[4][4];
#pragma unroll
  for (int i = 0; i < 4; ++i)
#pragma unroll
    for (int j = 0; j < 4; ++j) { v1[i][j] = -3.4e38f; v2[i][j] = -3.4e38f; c1[i][j] = 0; }

  int rs = t >> 1, hs = (t & 1) * 32;
  const unsigned short* aptr = zeb + (long)(r0 + rs) * 256 + hs;

  for (int ct = 0; ct < 8; ++ct) {
    int c0 = ct * 128;
    const unsigned short* bptr = cbb + (long)(c0 + rs) * 256 + hs;
    f32x4 acc[4][4];
#pragma unroll
    for (int i = 0; i < 4; ++i)
#pragma unroll
      for (int j = 0; j < 4; ++j) acc[i][j] = (f32x4){0.f, 0.f, 0.f, 0.f};

    for (int kt = 0; kt < 256; kt += 64) {
      __syncthreads();
      {
        const uint4* ap = (const uint4*)(aptr + kt);
        const uint4* bp = (const uint4*)(bptr + kt);
        uint4* ad = (uint4*)&A_s[rs * 72 + hs];
        uint4* bd = (uint4*)&B_s[rs * 72 + hs];
#pragma unroll
        for (int i = 0; i < 4; ++i) { ad[i] = ap[i]; bd[i] = bp[i]; }
      }
      __syncthreads();
#pragma unroll
      for (int kc = 0; kc < 2; ++kc) {
        short8 af[4], bfr[4];
#pragma unroll
        for (int x = 0; x < 4; ++x) {
          af[x] = *(const short8*)&A_s[(wr + x * 16 + m) * 72 + kc * 32 + q * 8];
          bfr[x] = *(const short8*)&B_s[(wc + x * 16 + m) * 72 + kc * 32 + q * 8];
        }
#pragma unroll
        for (int rt = 0; rt < 4; ++rt)
#pragma unroll
          for (int c2 = 0; c2 < 4; ++c2)
            acc[rt][c2] = mfma16(af[rt], bfr[c2], acc[rt][c2]);
      }
    }
#pragma unroll
    for (int rt = 0; rt < 4; ++rt)
#pragma unroll
      for (int c2 = 0; c2 < 4; ++c2) {
        int colb = c0 + wc + c2 * 16 + m;
#pragma unroll
        for (int r = 0; r < 4; ++r) {
          float v = acc[rt][c2][r];
          float nv2 = fmaxf(v2[rt][r], fminf(v, v1[rt][r]));
          if (v > v1[rt][r]) { c1[rt][r] = colb; v1[rt][r] = v; }
          v2[rt][r] = nv2;
        }
      }
  }

#pragma unroll
  for (int off = 1; off <= 8; off <<= 1) {
#pragma unroll
    for (int rt = 0; rt < 4; ++rt)
#pragma unroll
      for (int r = 0; r < 4; ++r) {
        float ov1 = __shfl_xor(v1[rt][r], off);
        float ov2 = __shfl_xor(v2[rt][r], off);
        int oc1 = __shfl_xor(c1[rt][r], off);
        float nv2 = fmaxf(fmaxf(v2[rt][r], ov2), fminf(v1[rt][r], ov1));
        if (ov1 > v1[rt][r] || (ov1 == v1[rt][r] && oc1 < c1[rt][r])) {
          v1[rt][r] = ov1; c1[rt][r] = oc1;
        }
        v2[rt][r] = nv2;
      }
  }
  if (m == 0) {
#pragma unroll
    for (int rt = 0; rt < 4; ++rt)
#pragma unroll
      for (int r = 0; r < 4; ++r) {
        int rloc = wr + rt * 16 + q * 4 + r;
        Lv1[rloc][wcb] = v1[rt][r];
        Lv2[rloc][wcb] = v2[rt][r];
        Lc1[rloc][wcb] = c1[rt][r];
      }
  }
  __syncthreads();
  if (t < 128) {
    float a1 = Lv1[t][0], a2 = Lv2[t][0];
    int ac = Lc1[t][0];
    float b1 = Lv1[t][1], b2 = Lv2[t][1];
    int bc = Lc1[t][1];
    float m2 = fmaxf(fmaxf(a2, b2), fminf(a1, b1));
    float m1; int mc;
    if (b1 > a1 || (b1 == a1 && bc < ac)) { m1 = b1; mc = bc; }
    else { m1 = a1; mc = ac; }
    idxc[r0 + t] = mc;
    if (m1 - m2 < 0.005f) {
      int p = atomicAdd(fixcnt, 1);
      fixlist[p] = r0 + t;
    }
  }
}

// ---------------- fp32 exact argmin fixup, code-parallel ----------------
__global__ __launch_bounds__(256) void fixup_part(
    const float* __restrict__ z_e, const float* __restrict__ cbn,
    const float* __restrict__ ze2, const float* __restrict__ cb2,
    const int* __restrict__ fixlist, const int* __restrict__ fixcnt,
    float* __restrict__ fixbv, int* __restrict__ fixbc) {
  int cnt = *fixcnt;
  int r0 = blockIdx.y * 128;
  if (r0 >= cnt) return;
  int ctile = blockIdx.x;
  int c0 = ctile * 128;
  __shared__ float As[16][132];
  __shared__ float Ws[16][132];
  __shared__ float rv[128][17];
  __shared__ int rc[128][17];
  __shared__ int rows_l[128];
  int t = threadIdx.x, tx = t & 15, ty = t >> 4;

  if (t < 128) rows_l[t] = fixlist[(r0 + t < cnt) ? (r0 + t) : 0];
  __syncthreads();

  float bestv[8];
  int bestc[8];
  float myze2[8];
#pragma unroll
  for (int i = 0; i < 8; ++i) {
    bestv[i] = 3.4e38f;
    bestc[i] = 0;
    int rl = ty * 4 + (i & 3) + ((i >> 2) * 64);
    myze2[i] = ze2[rows_l[rl]];
  }

  float acc[8][8];
#pragma unroll
  for (int i = 0; i < 8; ++i)
#pragma unroll
    for (int j = 0; j < 8; ++j) acc[i][j] = 0.0f;

  for (int kc = 0; kc < 16; ++kc) {
    int k0 = kc << 4;
    __syncthreads();
#pragma unroll
    for (int it = 0; it < 2; ++it) {
      int id = t + it * 256;
      int r = id >> 2;
      int kq = (id & 3) * 4;
      float4 v = *(const float4*)&z_e[(long)rows_l[r] * 256 + k0 + kq];
      As[kq + 0][r] = v.x; As[kq + 1][r] = v.y;
      As[kq + 2][r] = v.z; As[kq + 3][r] = v.w;
      float4 w = *(const float4*)&cbn[(long)(c0 + r) * 256 + k0 + kq];
      Ws[kq + 0][r] = w.x; Ws[kq + 1][r] = w.y;
      Ws[kq + 2][r] = w.z; Ws[kq + 3][r] = w.w;
    }
    __syncthreads();
#pragma unroll
    for (int k = 0; k < 16; ++k) {
      float av[8], bv[8];
      *(float4*)&av[0] = *(const float4*)&As[k][ty * 4];
      *(float4*)&av[4] = *(const float4*)&As[k][ty * 4 + 64];
      *(float4*)&bv[0] = *(const float4*)&Ws[k][tx * 4];
      *(float4*)&bv[4] = *(const float4*)&Ws[k][tx * 4 + 64];
#pragma unroll
      for (int i = 0; i < 8; ++i)
#pragma unroll
        for (int j = 0; j < 8; ++j)
          acc[i][j] = fmaf(av[i], bv[j], acc[i][j]);
    }
  }

  float cb2v[8];
  *(float4*)&cb2v[0] = *(const float4*)&cb2[c0 + tx * 4];
  *(float4*)&cb2v[4] = *(const float4*)&cb2[c0 + tx * 4 + 64];
#pragma unroll
  for (int i = 0; i < 8; ++i)
#pragma unroll
    for (int j = 0; j < 8; ++j) {
      int c = c0 + tx * 4 + (j & 3) + ((j >> 2) * 64);
      float d = (myze2[i] - 2.0f * acc[i][j]) + cb2v[j];
      if (d < bestv[i] || (d == bestv[i] && c < bestc[i])) {
        bestv[i] = d;
        bestc[i] = c;
      }
    }

  __syncthreads();
#pragma unroll
  for (int i = 0; i < 8; ++i) {
    int rl = ty * 4 + (i & 3) + ((i >> 2) * 64);
    rv[rl][tx] = bestv[i];
    rc[rl][tx] = bestc[i];
  }
  __syncthreads();
  if (t < 128 && r0 + t < cnt) {
    float bv = rv[t][0];
    int bc = rc[t][0];
    for (int j = 1; j < 16; ++j) {
      float v = rv[t][j];
      int c = rc[t][j];
      if (v < bv || (v == bv && c < bc)) { bv = v; bc = c; }
    }
    fixbv[(long)(r0 + t) * 8 + ctile] = bv;
    fixbc[(long)(r0 + t) * 8 + ctile] = bc;
  }
}

__global__ __launch_bounds__(256) void fixup_reduce(
    const float* __restrict__ fixbv, const int* __restrict__ fixbc,
    const int* __restrict__ fixlist, const int* __restrict__ fixcnt,
    int* __restrict__ idxc) {
  int cnt = *fixcnt;
  int i = blockIdx.x * 256 + threadIdx.x;
  if (i >= cnt) return;
  float bv = fixbv[(long)i * 8];
  int bc = fixbc[(long)i * 8];
#pragma unroll
  for (int j = 1; j < 8; ++j) {
    float v = fixbv[(long)i * 8 + j];
    int c = fixbc[(long)i * 8 + j];
    if (v < bv || (v == bv && c < bc)) { bv = v; bc = c; }
  }
  idxc[fixlist[i]] = bc;
}

// ---------------- row L2 normalize -> fp32 + bf16 + sumsq ----------------
__global__ __launch_bounds__(256) void rownorm_kernel(
    const float* __restrict__ in, float* __restrict__ outv,
    unsigned short* __restrict__ outb, float* __restrict__ outsq) {
  int wid = threadIdx.x >> 6, lane = threadIdx.x & 63;
  long row = (long)blockIdx.x * 4 + wid;
  const float* src = in + row * 256;
  float4 v = *(const float4*)&src[lane * 4];
  float s = v.x * v.x + v.y * v.y + v.z * v.z + v.w * v.w;
#pragma unroll
  for (int off = 32; off >= 1; off >>= 1) s += __shfl_xor(s, off);
  float denom = sqrtf(s) + 1e-8f;
  float4 o;
  o.x = v.x / denom; o.y = v.y / denom; o.z = v.z / denom; o.w = v.w / denom;
  *(float4*)&outv[row * 256 + lane * 4] = o;
  ushort4 ob;
  ob.x = f2bf(o.x); ob.y = f2bf(o.y); ob.z = f2bf(o.z); ob.w = f2bf(o.w);
  *(ushort4*)&outb[row * 256 + lane * 4] = ob;
  float s2 = o.x * o.x + o.y * o.y + o.z * o.z + o.w * o.w;
#pragma unroll
  for (int off = 32; off >= 1; off >>= 1) s2 += __shfl_xor(s2, off);
  if (lane == 0) outsq[row] = s2;
}

// ---------------- W [K][N] fp32 -> Wt [N][K] bf16 (single plane) ----------------
__global__ __launch_bounds__(256) void transpose_w_kernel(
    const float* __restrict__ W, unsigned short* __restrict__ Wt, int K, int N) {
  __shared__ float tile[32][33];
  int n0 = blockIdx.x * 32, k0 = blockIdx.y * 32;
  int tx = threadIdx.x & 31, ty = threadIdx.x >> 5;
#pragma unroll
  for (int i = 0; i < 32; i += 8)
    tile[ty + i][tx] = W[(long)(k0 + ty + i) * N + n0 + tx];
  __syncthreads();
#pragma unroll
  for (int i = 0; i < 32; i += 8)
    Wt[(long)(n0 + ty + i) * K + k0 + tx] = f2bf(tile[tx][ty + i]);
}

// ---------------- decoder last layer (bf16 in, dout=32) + recon loss ----------------
__global__ __launch_bounds__(256) void dec2_kernel(
    const unsigned short* __restrict__ D1, const float* __restrict__ W,
    const float* __restrict__ bias, const float* __restrict__ action,
    const float* __restrict__ dimw, float* __restrict__ ahat,
    float* __restrict__ accum) {
  __shared__ float As[16][66];
  __shared__ float Ws[16][32];
  int t = threadIdx.x, tx = t & 7, ty = t >> 3;
  int r0 = blockIdx.x * 64;
  float acc[2][4] = {{0, 0, 0, 0}, {0, 0, 0, 0}};

  for (int kc = 0; kc < 32; ++kc) {
    int k0 = kc << 4;
    __syncthreads();
    {
      int r = t >> 2, kq = (t & 3) * 4;
      ushort4 u = *(const ushort4*)&D1[(long)(r0 + r) * 512 + k0 + kq];
      As[kq + 0][r] = bf2f(u.x); As[kq + 1][r] = bf2f(u.y);
      As[kq + 2][r] = bf2f(u.z); As[kq + 3][r] = bf2f(u.w);
      if (t < 128) {
        int k = t >> 3, cq = (t & 7) * 4;
        *(float4*)&Ws[k][cq] = *(const float4*)&W[(long)(k0 + k) * 32 + cq];
      }
    }
    __syncthreads();
#pragma unroll
    for (int k = 0; k < 16; ++k) {
      float2 a = *(const float2*)&As[k][ty * 2];
      float4 b = *(const float4*)&Ws[k][tx * 4];
      acc[0][0] = fmaf(a.x, b.x, acc[0][0]);
      acc[0][1] = fmaf(a.x, b.y, acc[0][1]);
      acc[0][2] = fmaf(a.x, b.z, acc[0][2]);
      acc[0][3] = fmaf(a.x, b.w, acc[0][3]);
      acc[1][0] = fmaf(a.y, b.x, acc[1][0]);
      acc[1][1] = fmaf(a.y, b.y, acc[1][1]);
      acc[1][2] = fmaf(a.y, b.z, acc[1][2]);
      acc[1][3] = fmaf(a.y, b.w, acc[1][3]);
    }
  }

  float4 bb = *(const float4*)&bias[tx * 4];
  float4 dw = *(const float4*)&dimw[tx * 4];
  float lsum = 0.0f;
#pragma unroll
  for (int rr = 0; rr < 2; ++rr) {
    long row = r0 + ty * 2 + rr;
    float4 av = *(const float4*)&action[row * 32 + tx * 4];
    float4 o;
    o.x = acc[rr][0] + bb.x; o.y = acc[rr][1] + bb.y;
    o.z = acc[rr][2] + bb.z; o.w = acc[rr][3] + bb.w;
    *(float4*)&ahat[row * 32 + tx * 4] = o;
    float ex = av.x - o.x, ey = av.y - o.y, ez = av.z - o.z, ew = av.w - o.w;
    lsum += ex * ex * dw.x + ey * ey * dw.y + ez * ez * dw.z + ew * ew * dw.w;
  }
#pragma unroll
  for (int off = 32; off >= 1; off >>= 1) lsum += __shfl_xor(lsum, off);
  __shared__ float red[4];
  int wid = t >> 6, lane = t & 63;
  if (lane == 0) red[wid] = lsum;
  __syncthreads();
  if (t == 0) atomicAdd(accum, red[0] + red[1] + red[2] + red[3]);
}

// ---------------- commit loss + idx->float (fused) ----------------
__global__ __launch_bounds__(256) void commit_idx_kernel(
    const float* __restrict__ z_e, const float* __restrict__ cbn,
    const int* __restrict__ idx, float* __restrict__ accum,
    float* __restrict__ outIdx) {
  int wid = threadIdx.x >> 6, lane = threadIdx.x & 63;
  long row = (long)blockIdx.x * 4 + wid;
  int k = idx[row];
  float4 a = *(const float4*)&z_e[row * 256 + lane * 4];
  float4 b = *(const float4*)&cbn[(long)k * 256 + lane * 4];
  float dx = a.x - b.x, dy = a.y - b.y, dz = a.z - b.z, dw = a.w - b.w;
  float s = dx * dx + dy * dy + dz * dz + dw * dw;
#pragma unroll
  for (int off = 32; off >= 1; off >>= 1) s += __shfl_xor(s, off);
  __shared__ float red[4];
  if (lane == 0) {
    red[wid] = s;
    outIdx[row] = (float)k;
  }
  __syncthreads();
  if (threadIdx.x == 0) atomicAdd(accum, red[0] + red[1] + red[2] + red[3]);
}

__global__ void zero_kernel(float* __restrict__ acc, int* __restrict__ cnts) {
  if (threadIdx.x < 2) acc[threadIdx.x] = 0.0f;
  if (threadIdx.x < 32) cnts[threadIdx.x] = 0;
}

__global__ void finalize_kernel(const float* __restrict__ acc,
                                float* __restrict__ out) {
  out[0] = acc[0] / (65536.0f * 32.0f);
  float cl = acc[1] / (65536.0f * 256.0f);
  out[1] = cl;
  out[2] = cl;
}

extern "C" void kernel_launch(void* const* d_in, const int* in_sizes, int n_in,
                              void* d_out, int out_size, void* d_ws,
                              size_t ws_size, hipStream_t stream) {
  const float* action = (const float*)d_in[0];
  const float* dimw = (const float*)d_in[1];
  const float* ew0 = (const float*)d_in[2];
  const float* eb0 = (const float*)d_in[3];
  const float* ew1 = (const float*)d_in[4];
  const float* eb1 = (const float*)d_in[5];
  const float* ew2 = (const float*)d_in[6];
  const float* eb2 = (const float*)d_in[7];
  const float* dw0 = (const float*)d_in[8];
  const float* db0 = (const float*)d_in[9];
  const float* dw1 = (const float*)d_in[10];
  const float* db1 = (const float*)d_in[11];
  const float* dw2 = (const float*)d_in[12];
  const float* db2 = (const float*)d_in[13];
  const float* cb = (const float*)d_in[14];
  float* out = (float*)d_out;
  char* ws = (char*)d_ws;

  // fixed region
  const size_t fixed_b = 1048576 + 4096 + 524288 + 524288 + 1048576 +
                         3145728 + 1572864 + 256;
  // per-row: P0 2560 + P1 4096 + ze2 4 + idxc 4 + fixlist 4 + partials 64
  int R = N_ROWS;
  while (R > 2048) {
    if (fixed_b + (size_t)R * 6732 + 65536 <= ws_size) break;
    R >>= 1;
  }

  size_t off = 0;
  float* cbn = (float*)(ws + off); off += 1048576;
  float* cb2 = (float*)(ws + off); off += 4096;
  unsigned short* cbb = (unsigned short*)(ws + off); off += 524288;
  unsigned short* dwt0 = (unsigned short*)(ws + off); off += 524288;
  unsigned short* dwt1 = (unsigned short*)(ws + off); off += 1048576;
  unsigned short* ewf1 = (unsigned short*)(ws + off); off += 3145728;  // enc1 Bfrag: 64cb x 16kb x 3 x 512
  unsigned short* ewf2 = (unsigned short*)(ws + off); off += 1572864;  // enc2 Bfrag: 16cb x 32kb x 3 x 512
  float* accum = (float*)(ws + off);
  int* fixcnts = (int*)(ws + off + 64); off += 256;
  float* ze2 = (float*)(ws + off); off += (size_t)R * 4;
  int* idxc = (int*)(ws + off); off += (size_t)R * 4;
  int* fixlist = (int*)(ws + off); off += (size_t)R * 4;
  float* fixbv = (float*)(ws + off); off += (size_t)R * 32;
  int* fixbc = (int*)(ws + off); off += (size_t)R * 32;
  char* P0 = ws + off; off += (size_t)R * 2560;
  char* P1 = ws + off; off += (size_t)R * 4096;

  float* e0 = (float*)P0;                         // R x 512 f32 (first 2048 B/row)
  float* e1 = (float*)P1;                         // R x 1024 f32
  float* zbuf = (float*)P0;                       // R x 256 f32
  float* z_e = (float*)(P0 + (size_t)R * 1024);   // R x 256 f32
  unsigned short* zeb = (unsigned short*)(P0 + (size_t)R * 2048);  // R x 256 bf16
  unsigned short* D0b = (unsigned short*)P1;                       // R x 1024 bf16
  unsigned short* D1b = (unsigned short*)(P1 + (size_t)R * 2048);  // R x 512 bf16

  zero_kernel<<<1, 64, 0, stream>>>(accum, fixcnts);
  rownorm_kernel<<<256, 256, 0, stream>>>(cb, cbn, cbb, cb2);
  transpose_w_kernel<<<dim3(32, 8), 256, 0, stream>>>(dw0, dwt0, 256, 1024);
  transpose_w_kernel<<<dim3(16, 32), 256, 0, stream>>>(dw1, dwt1, 1024, 512);
  frag_pack_kernel<<<dim3(64, 16), 64, 0, stream>>>(ew1, ewf1, 512, 1024);
  frag_pack_kernel<<<dim3(16, 32), 64, 0, stream>>>(ew2, ewf2, 1024, 256);

  for (int base = 0; base < N_ROWS; base += R) {
    int ci = base / R;
    const float* act_c = action + (size_t)base * 32;
    float* out_c = out + (size_t)base * 32;
    int* fixcnt = &fixcnts[ci];

    // encoder: e0 (fp32) -> P0, e1 (bf16x3 MFMA, frag-B) -> P1, z -> P0
    gemm_kernel<true><<<dim3(4, R / 128), 256, 0, stream>>>(
        act_c, ew0, eb0, e0, 32, 512);
    mfma3_gemm<true><<<dim3(8, R / 128), 256, 0, stream>>>(
        e0, ewf1, eb1, e1, 512, 1024);
    mfma3_gemm<false><<<dim3(2, R / 128), 256, 0, stream>>>(
        e1, ewf2, eb2, zbuf, 1024, 256);

    rownorm_kernel<<<R / 4, 256, 0, stream>>>(zbuf, z_e, zeb, ze2);

    dist_mfma<<<R / 128, 256, 0, stream>>>(zeb, cbb, idxc, fixcnt, fixlist);
    fixup_part<<<dim3(8, R / 128), 256, 0, stream>>>(
        z_e, cbn, ze2, cb2, fixlist, fixcnt, fixbv, fixbc);
    fixup_reduce<<<R / 256, 256, 0, stream>>>(fixbv, fixbc, fixlist, fixcnt,
                                              idxc);

    commit_idx_kernel<<<R / 4, 256, 0, stream>>>(z_e, cbn, idxc, &accum[1],
                                                 out + 2097152 + base);

    // decoder: d0 -> D0b (e1 dead), d1 -> D1b, dec2 + recon loss
    mfma_gemm<true, true><<<dim3(8, R / 128), 256, 0, stream>>>(
        cbb, dwt0, db0, D0b, 256, 1024, idxc);
    mfma_gemm<true, false><<<dim3(4, R / 128), 256, 0, stream>>>(
        D0b, dwt1, db1, D1b, 1024, 512, nullptr);
    dec2_kernel<<<R / 64, 256, 0, stream>>>(D1b, dw2, db2, act_c, dimw, out_c,
                                            &accum[0]);
  }

  finalize_kernel<<<1, 1, 0, stream>>>(accum, out + 2162688);
}